// Round 1
// baseline (496.042 us; speedup 1.0000x reference)
//
#include <hip/hip_runtime.h>
#include <hip/hip_bf16.h>

typedef __attribute__((ext_vector_type(8))) short short8;
typedef __attribute__((ext_vector_type(4))) short short4v;
typedef __attribute__((ext_vector_type(4))) float f32x4;

#define MFMA(A,B,C) __builtin_amdgcn_mfma_f32_16x16x32_bf16(A,B,C,0,0,0)

__device__ __forceinline__ short f2bs(float f) {
    __hip_bfloat16 h = __float2bfloat16(f);
    union { __hip_bfloat16 h; short s; } u; u.h = h; return u.s;
}

// ---------------- cast fp32 -> bf16, vectorized x4 ----------------
__global__ __launch_bounds__(256) void cast_bf16_k(const float* __restrict__ X,
                                                   short* __restrict__ Y, int n4) {
    int i = blockIdx.x * 256 + threadIdx.x;
    if (i >= n4) return;
    const float4 v = *(const float4*)(X + (size_t)i * 4);
    short4v o;
    o.x = f2bs(v.x); o.y = f2bs(v.y); o.z = f2bs(v.z); o.w = f2bs(v.w);
    *(short4v*)(Y + (size_t)i * 4) = o;
}

// ---------------- transpose + cast: Wt[n][k] = W[k][n] ----------------
__global__ __launch_bounds__(256) void transpose_cast_k(const float* __restrict__ W,
                                                        short* __restrict__ Wt, int K, int N) {
    __shared__ float tile[32][33];
    int n0 = blockIdx.x * 32, k0 = blockIdx.y * 32;
    int tx = threadIdx.x, ty = threadIdx.y;
    #pragma unroll
    for (int i = 0; i < 32; i += 8)
        tile[ty + i][tx] = W[(size_t)(k0 + ty + i) * N + n0 + tx];
    __syncthreads();
    #pragma unroll
    for (int i = 0; i < 32; i += 8)
        Wt[(size_t)(n0 + ty + i) * K + k0 + tx] = f2bs(tile[tx][ty + i]);
}

// ---------------- GEMM: C = A(M,K) @ Bt(N,K)^T, bf16 in, fp32 acc ----------------
// epi: 0 = fp32 C row-major; 1 = rope + pack bf16 (b,nheads,2048,64); 2 = pack only
__global__ __launch_bounds__(256) void gemm_bt(
    const short* __restrict__ A, const short* __restrict__ Bt,
    float* __restrict__ Cf, short* __restrict__ Cp,
    const float* __restrict__ rc, const float* __restrict__ rs,
    int M, int N, int K, int epi, int nheads)
{
    __shared__ short As[128 * 64];
    __shared__ short Bs[128 * 64];
    const int t = threadIdx.x;
    const int l = t & 63, w = t >> 6;
    const int lo = l & 15, hi = l >> 4;
    const int wm = w >> 1, wn = w & 1;
    const int tm = blockIdx.x * 128, tn = blockIdx.y * 128;

    const f32x4 z4 = {0.f, 0.f, 0.f, 0.f};
    f32x4 acc[4][4];
    #pragma unroll
    for (int m = 0; m < 4; ++m)
        #pragma unroll
        for (int n = 0; n < 4; ++n) acc[m][n] = z4;

    for (int k0 = 0; k0 < K; k0 += 64) {
        #pragma unroll
        for (int it = 0; it < 4; ++it) {
            int c = it * 256 + t;
            int row = c >> 3, slot = c & 7;
            int sw = (slot ^ (row & 7)) << 3;
            short8 va = *(const short8*)(A + (size_t)(tm + row) * K + k0 + slot * 8);
            *(short8*)(As + row * 64 + sw) = va;
            short8 vb = *(const short8*)(Bt + (size_t)(tn + row) * K + k0 + slot * 8);
            *(short8*)(Bs + row * 64 + sw) = vb;
        }
        __syncthreads();
        #pragma unroll
        for (int ks = 0; ks < 2; ++ks) {
            short8 af[4], bfr[4];
            #pragma unroll
            for (int m = 0; m < 4; ++m) {
                int row = wm * 64 + m * 16 + lo;
                int slot = ks * 4 + hi;
                af[m] = *(const short8*)(As + row * 64 + ((slot ^ (row & 7)) << 3));
            }
            #pragma unroll
            for (int n = 0; n < 4; ++n) {
                int row = wn * 64 + n * 16 + lo;
                int slot = ks * 4 + hi;
                bfr[n] = *(const short8*)(Bs + row * 64 + ((slot ^ (row & 7)) << 3));
            }
            #pragma unroll
            for (int m = 0; m < 4; ++m)
                #pragma unroll
                for (int n = 0; n < 4; ++n)
                    acc[m][n] = MFMA(af[m], bfr[n], acc[m][n]);
        }
        __syncthreads();
    }

    if (epi == 0) {
        #pragma unroll
        for (int m = 0; m < 4; ++m)
            #pragma unroll
            for (int r = 0; r < 4; ++r) {
                int row = tm + wm * 64 + m * 16 + hi * 4 + r;
                #pragma unroll
                for (int n = 0; n < 4; ++n) {
                    int col = tn + wn * 64 + n * 16 + lo;
                    Cf[(size_t)row * N + col] = acc[m][n][r];
                }
            }
    } else if (epi == 1) {
        #pragma unroll
        for (int m = 0; m < 4; ++m)
            #pragma unroll
            for (int r = 0; r < 4; ++r) {
                int row = tm + wm * 64 + m * 16 + hi * 4 + r;
                int b = row >> 11, s = row & 2047;
                #pragma unroll
                for (int n = 0; n < 2; ++n) {
                    int col = tn + wn * 64 + n * 16 + lo;
                    int h = col >> 6, d = col & 63;  // d < 32 here
                    float x1 = acc[m][n][r], x2 = acc[m][n + 2][r];
                    float c = rc[s * 32 + d], sn = rs[s * 32 + d];
                    size_t base = (((size_t)b * nheads + h) * 2048 + s) * 64;
                    Cp[base + d]      = f2bs(x1 * c - x2 * sn);
                    Cp[base + d + 32] = f2bs(x1 * sn + x2 * c);
                }
            }
    } else {
        #pragma unroll
        for (int m = 0; m < 4; ++m)
            #pragma unroll
            for (int r = 0; r < 4; ++r) {
                int row = tm + wm * 64 + m * 16 + hi * 4 + r;
                int b = row >> 11, s = row & 2047;
                #pragma unroll
                for (int n = 0; n < 4; ++n) {
                    int col = tn + wn * 64 + n * 16 + lo;
                    int h = col >> 6, d = col & 63;
                    size_t base = (((size_t)b * nheads + h) * 2048 + s) * 64;
                    Cp[base + d] = f2bs(acc[m][n][r]);
                }
            }
    }
}

// ---------------- flash attention: block = (qt, h, b), 4 waves x 16 q-rows ----------------
__global__ __launch_bounds__(256) void attn_k(
    const short* __restrict__ Qp, const short* __restrict__ Kp, const short* __restrict__ Vp,
    short* __restrict__ Ab)
{
    __shared__ short Ks[64 * 64];
    __shared__ short Vts[64 * 64];
    __shared__ short Ps[64 * 64];
    const int t = threadIdx.x, l = t & 63, w = t >> 6;
    const int lo = l & 15, hi = l >> 4;
    const int qt = blockIdx.x, h = blockIdx.y, b = blockIdx.z;
    const int kvh = h >> 2;
    const size_t qbase = (size_t)(b * 32 + h) * 2048 * 64;
    const size_t kbase = (size_t)(b * 8 + kvh) * 2048 * 64;

    short8 qf[2];
    {
        int qrow = qt * 64 + w * 16 + lo;
        qf[0] = *(const short8*)(Qp + qbase + (size_t)qrow * 64 + hi * 8);
        qf[1] = *(const short8*)(Qp + qbase + (size_t)qrow * 64 + 32 + hi * 8);
    }

    const f32x4 z4 = {0.f, 0.f, 0.f, 0.f};
    float m_run[4], l_run[4];
    f32x4 oacc[4];
    #pragma unroll
    for (int r = 0; r < 4; ++r) { m_run[r] = -1e30f; l_run[r] = 0.f; }
    #pragma unroll
    for (int n = 0; n < 4; ++n) oacc[n] = z4;

    const int qglob = qt * 64 + w * 16 + hi * 4;
    short* Pw = Ps + w * 16 * 64;

    for (int kt = 0; kt <= qt; ++kt) {
        // stage K (swizzled) and V transposed (swizzled)
        #pragma unroll
        for (int it = 0; it < 2; ++it) {
            int c = it * 256 + t;
            int row = c >> 3, slot = c & 7;
            short8 vk = *(const short8*)(Kp + kbase + (size_t)(kt * 64 + row) * 64 + slot * 8);
            *(short8*)(Ks + row * 64 + ((slot ^ (row & 7)) << 3)) = vk;
            short8 vv = *(const short8*)(Vp + kbase + (size_t)(kt * 64 + row) * 64 + slot * 8);
            #pragma unroll
            for (int j = 0; j < 8; ++j) {
                int d = slot * 8 + j;
                Vts[d * 64 + (((row >> 3) ^ (d & 7)) << 3) + (row & 7)] = vv[j];
            }
        }
        __syncthreads();

        // S = Q K^T
        f32x4 sacc[4];
        #pragma unroll
        for (int n = 0; n < 4; ++n) sacc[n] = z4;
        #pragma unroll
        for (int ks = 0; ks < 2; ++ks) {
            int slot = ks * 4 + hi;
            #pragma unroll
            for (int n = 0; n < 4; ++n) {
                int krow = n * 16 + lo;
                short8 kf = *(const short8*)(Ks + krow * 64 + ((slot ^ (krow & 7)) << 3));
                sacc[n] = MFMA(qf[ks], kf, sacc[n]);
            }
        }

        // scale + causal mask + online softmax
        float pv[4][4], pm[4];
        #pragma unroll
        for (int r = 0; r < 4; ++r) pm[r] = -1e30f;
        #pragma unroll
        for (int n = 0; n < 4; ++n) {
            int kglob = kt * 64 + n * 16 + lo;
            #pragma unroll
            for (int r = 0; r < 4; ++r) {
                float sv = sacc[n][r] * 0.125f;
                sv = (kglob > qglob + r) ? -1e30f : sv;
                pv[n][r] = sv;
                pm[r] = fmaxf(pm[r], sv);
            }
        }
        #pragma unroll
        for (int d = 1; d < 16; d <<= 1)
            #pragma unroll
            for (int r = 0; r < 4; ++r)
                pm[r] = fmaxf(pm[r], __shfl_xor(pm[r], d, 64));

        float al[4], rsum[4];
        #pragma unroll
        for (int r = 0; r < 4; ++r) {
            float mn = fmaxf(m_run[r], pm[r]);
            al[r] = __expf(m_run[r] - mn);
            m_run[r] = mn;
            rsum[r] = 0.f;
        }
        #pragma unroll
        for (int n = 0; n < 4; ++n)
            #pragma unroll
            for (int r = 0; r < 4; ++r) {
                float p = __expf(pv[n][r] - m_run[r]);
                pv[n][r] = p;
                rsum[r] += p;
            }
        #pragma unroll
        for (int d = 1; d < 16; d <<= 1)
            #pragma unroll
            for (int r = 0; r < 4; ++r)
                rsum[r] += __shfl_xor(rsum[r], d, 64);
        #pragma unroll
        for (int r = 0; r < 4; ++r) l_run[r] = l_run[r] * al[r] + rsum[r];
        #pragma unroll
        for (int n = 0; n < 4; ++n) {
            oacc[n].x *= al[0]; oacc[n].y *= al[1]; oacc[n].z *= al[2]; oacc[n].w *= al[3];
        }

        // P -> bf16 -> per-wave LDS strip (swizzled)
        #pragma unroll
        for (int n = 0; n < 4; ++n) {
            int col = n * 16 + lo;
            #pragma unroll
            for (int r = 0; r < 4; ++r) {
                int rl = hi * 4 + r;
                Pw[rl * 64 + (((col >> 3) ^ (rl & 7)) << 3) + (col & 7)] = f2bs(pv[n][r]);
            }
        }
        __syncthreads();

        // O += P V
        #pragma unroll
        for (int ks = 0; ks < 2; ++ks) {
            int slot = ks * 4 + hi;
            short8 pf = *(const short8*)(Pw + lo * 64 + ((slot ^ (lo & 7)) << 3));
            #pragma unroll
            for (int n = 0; n < 4; ++n) {
                int d = n * 16 + lo;
                short8 vf = *(const short8*)(Vts + d * 64 + ((slot ^ (d & 7)) << 3));
                oacc[n] = MFMA(pf, vf, oacc[n]);
            }
        }
        __syncthreads();
    }

    // write attn out, packed (b, s, h*64+d) bf16
    const size_t abase = (size_t)b * 2048 * 2048 + (size_t)h * 64;
    #pragma unroll
    for (int n = 0; n < 4; ++n) {
        int d = n * 16 + lo;
        #pragma unroll
        for (int r = 0; r < 4; ++r) {
            int s = qt * 64 + w * 16 + hi * 4 + r;
            Ab[abase + (size_t)s * 2048 + d] = f2bs(oacc[n][r] / l_run[r]);
        }
    }
}

extern "C" void kernel_launch(void* const* d_in, const int* in_sizes, int n_in,
                              void* d_out, int out_size, void* d_ws, size_t ws_size,
                              hipStream_t stream)
{
    const float* x  = (const float*)d_in[0];
    const float* Wq = (const float*)d_in[1];
    const float* Wk = (const float*)d_in[2];
    const float* Wv = (const float*)d_in[3];
    const float* Wo = (const float*)d_in[4];
    const float* rc = (const float*)d_in[5];
    const float* rs = (const float*)d_in[6];
    float* out = (float*)d_out;
    char* ws = (char*)d_ws;

    size_t off = 0;
    short* x_bf = (short*)(ws + off); off += (size_t)4096 * 2048 * 2;
    short* Wq_t = (short*)(ws + off); off += (size_t)2048 * 2048 * 2;
    short* Wk_t = (short*)(ws + off); off += (size_t)512 * 2048 * 2;
    short* Wv_t = (short*)(ws + off); off += (size_t)512 * 2048 * 2;
    short* Wo_t = (short*)(ws + off); off += (size_t)2048 * 2048 * 2;
    short* Qp   = (short*)(ws + off); off += (size_t)2 * 32 * 2048 * 64 * 2;
    short* Kp   = (short*)(ws + off); off += (size_t)2 * 8 * 2048 * 64 * 2;
    short* Vp   = (short*)(ws + off); off += (size_t)2 * 8 * 2048 * 64 * 2;
    short* Ab   = (short*)(ws + off); off += (size_t)4096 * 2048 * 2;
    if (off > ws_size) return;  // ws too small: fail loudly (validation will catch)

    cast_bf16_k<<<8192, 256, 0, stream>>>(x, x_bf, 2097152);
    transpose_cast_k<<<dim3(64, 64), dim3(32, 8), 0, stream>>>(Wq, Wq_t, 2048, 2048);
    transpose_cast_k<<<dim3(16, 64), dim3(32, 8), 0, stream>>>(Wk, Wk_t, 2048, 512);
    transpose_cast_k<<<dim3(16, 64), dim3(32, 8), 0, stream>>>(Wv, Wv_t, 2048, 512);
    transpose_cast_k<<<dim3(64, 64), dim3(32, 8), 0, stream>>>(Wo, Wo_t, 2048, 2048);

    // Q/K with fused RoPE + pack; V pack only
    gemm_bt<<<dim3(32, 16), 256, 0, stream>>>(x_bf, Wq_t, nullptr, Qp, rc, rs, 4096, 2048, 2048, 1, 32);
    gemm_bt<<<dim3(32, 4),  256, 0, stream>>>(x_bf, Wk_t, nullptr, Kp, rc, rs, 4096, 512, 2048, 1, 8);
    gemm_bt<<<dim3(32, 4),  256, 0, stream>>>(x_bf, Wv_t, nullptr, Vp, rc, rs, 4096, 512, 2048, 2, 8);

    attn_k<<<dim3(32, 32, 2), 256, 0, stream>>>(Qp, Kp, Vp, Ab);

    gemm_bt<<<dim3(32, 16), 256, 0, stream>>>(Ab, Wo_t, out, nullptr, nullptr, nullptr, 4096, 2048, 2048, 0, 0);
}

// Round 2
// 308.203 us; speedup vs baseline: 1.6095x; 1.6095x over previous
//
#include <hip/hip_runtime.h>
#include <hip/hip_bf16.h>

typedef __attribute__((ext_vector_type(8))) short short8;
typedef __attribute__((ext_vector_type(4))) short short4v;
typedef __attribute__((ext_vector_type(4))) float f32x4;

#define MFMA(A,B,C) __builtin_amdgcn_mfma_f32_16x16x32_bf16(A,B,C,0,0,0)
// swizzle: 3 bits from row bits {0,1,3} so fragment reads spread 8 bank-quads
#define SW(row) ((((row) & 3)) | (((row) >> 1) & 4))

__device__ __forceinline__ short f2bs(float f) {
    __hip_bfloat16 h = __float2bfloat16(f);
    union { __hip_bfloat16 h; short s; } u; u.h = h; return u.s;
}

__device__ __forceinline__ void async16(void* lds, const void* g) {
    __builtin_amdgcn_global_load_lds(
        (const __attribute__((address_space(1))) unsigned int*)g,
        (__attribute__((address_space(3))) unsigned int*)lds, 16, 0, 0);
}

// ---------------- cast fp32 -> bf16, vectorized x4 ----------------
__global__ __launch_bounds__(256) void cast_bf16_k(const float* __restrict__ X,
                                                   short* __restrict__ Y, int n4) {
    int i = blockIdx.x * 256 + threadIdx.x;
    if (i >= n4) return;
    const float4 v = *(const float4*)(X + (size_t)i * 4);
    short4v o;
    o.x = f2bs(v.x); o.y = f2bs(v.y); o.z = f2bs(v.z); o.w = f2bs(v.w);
    *(short4v*)(Y + (size_t)i * 4) = o;
}

// ---------------- transpose + cast: Wt[n][k] = W[k][n] ----------------
__global__ __launch_bounds__(256) void transpose_cast_k(const float* __restrict__ W,
                                                        short* __restrict__ Wt, int K, int N) {
    __shared__ float tile[32][33];
    int n0 = blockIdx.x * 32, k0 = blockIdx.y * 32;
    int tx = threadIdx.x, ty = threadIdx.y;
    #pragma unroll
    for (int i = 0; i < 32; i += 8)
        tile[ty + i][tx] = W[(size_t)(k0 + ty + i) * N + n0 + tx];
    __syncthreads();
    #pragma unroll
    for (int i = 0; i < 32; i += 8)
        Wt[(size_t)(n0 + ty + i) * K + k0 + tx] = f2bs(tile[tx][ty + i]);
}

// ---------------- GEMM: C = A(M,K) @ Bt(N,K)^T, bf16 in, fp32 acc ----------------
// epi 0: fp32 C row-major
// epi 1: rope + pack bf16 (b, nheads, 2048, 64) into Cp
// epi 3: merged KV: cols<512 -> rope+pack K (8 heads) into Cp; cols>=512 -> V transposed into Cv (b,8,64,2048)
__global__ __launch_bounds__(256) void gemm_bt(
    const short* __restrict__ A, const short* __restrict__ Bt,
    float* __restrict__ Cf, short* __restrict__ Cp, short* __restrict__ Cv,
    const float* __restrict__ rc, const float* __restrict__ rs,
    int M, int N, int K, int epi, int nheads)
{
    __shared__ short As[128 * 64];
    __shared__ short Bs[128 * 64];
    const int t = threadIdx.x;
    const int l = t & 63, w = t >> 6;
    const int lo = l & 15, hi = l >> 4;
    const int wm = w >> 1, wn = w & 1;
    const int tm = blockIdx.x * 128, tn = blockIdx.y * 128;
    const int lr = l >> 3, ls = l & 7;

    const f32x4 z4 = {0.f, 0.f, 0.f, 0.f};
    f32x4 acc[4][4];
    #pragma unroll
    for (int m = 0; m < 4; ++m)
        #pragma unroll
        for (int n = 0; n < 4; ++n) acc[m][n] = z4;

    for (int k0 = 0; k0 < K; k0 += 64) {
        #pragma unroll
        for (int i = 0; i < 4; ++i) {
            int g = w * 4 + i;
            int row = g * 8 + lr;
            int gs = ls ^ SW(row);
            async16(As + g * 512, A + (size_t)(tm + row) * K + k0 + gs * 8);
            async16(Bs + g * 512, Bt + (size_t)(tn + row) * K + k0 + gs * 8);
        }
        __syncthreads();
        #pragma unroll
        for (int ks = 0; ks < 2; ++ks) {
            const int slot = ks * 4 + hi;
            short8 af[4], bfr[4];
            #pragma unroll
            for (int m = 0; m < 4; ++m) {
                int row = wm * 64 + m * 16 + lo;
                af[m] = *(const short8*)(As + row * 64 + ((slot ^ SW(row)) << 3));
            }
            #pragma unroll
            for (int n = 0; n < 4; ++n) {
                int row = wn * 64 + n * 16 + lo;
                bfr[n] = *(const short8*)(Bs + row * 64 + ((slot ^ SW(row)) << 3));
            }
            #pragma unroll
            for (int m = 0; m < 4; ++m)
                #pragma unroll
                for (int n = 0; n < 4; ++n)
                    acc[m][n] = MFMA(af[m], bfr[n], acc[m][n]);
        }
        __syncthreads();
    }

    if (epi == 0) {
        #pragma unroll
        for (int m = 0; m < 4; ++m)
            #pragma unroll
            for (int r = 0; r < 4; ++r) {
                int row = tm + wm * 64 + m * 16 + hi * 4 + r;
                #pragma unroll
                for (int n = 0; n < 4; ++n) {
                    int col = tn + wn * 64 + n * 16 + lo;
                    Cf[(size_t)row * N + col] = acc[m][n][r];
                }
            }
    } else if (epi == 1 || (epi == 3 && (tn + wn * 64) < 512)) {
        int nh = (epi == 3) ? 8 : nheads;
        #pragma unroll
        for (int m = 0; m < 4; ++m)
            #pragma unroll
            for (int r = 0; r < 4; ++r) {
                int row = tm + wm * 64 + m * 16 + hi * 4 + r;
                int b = row >> 11, s = row & 2047;
                #pragma unroll
                for (int n = 0; n < 2; ++n) {
                    int col = tn + wn * 64 + n * 16 + lo;
                    int h = col >> 6, d = col & 63;  // d < 32 here
                    float x1 = acc[m][n][r], x2 = acc[m][n + 2][r];
                    float c = rc[s * 32 + d], sn = rs[s * 32 + d];
                    size_t base = (((size_t)b * nh + h) * 2048 + s) * 64;
                    Cp[base + d]      = f2bs(x1 * c - x2 * sn);
                    Cp[base + d + 32] = f2bs(x1 * sn + x2 * c);
                }
            }
    } else {  // epi 3, V half: write transposed (b, kvh, d, s)
        #pragma unroll
        for (int m = 0; m < 4; ++m)
            #pragma unroll
            for (int r = 0; r < 4; ++r) {
                int row = tm + wm * 64 + m * 16 + hi * 4 + r;
                int b = row >> 11, s = row & 2047;
                #pragma unroll
                for (int n = 0; n < 4; ++n) {
                    int col = tn + wn * 64 + n * 16 + lo - 512;
                    int h = col >> 6, d = col & 63;
                    Cv[(((size_t)b * 8 + h) * 64 + d) * 2048 + s] = f2bs(acc[m][n][r]);
                }
            }
    }
}

// ---------------- flash attention ----------------
// block = (qtile rev, h, b), 4 waves x 32 q-rows (2 groups of 16), KVBLK=64.
// Swapped QK^T (mfma(K,Q)) with sigma-permuted K rows so each lane's P values
// ARE its PV A-fragment (no LDS roundtrip, no shuffles). V pre-transposed in global.
__global__ __launch_bounds__(256) void attn_k(
    const short* __restrict__ Qp, const short* __restrict__ Kp, const short* __restrict__ Vt,
    short* __restrict__ Ab)
{
    __shared__ short Ks[64 * 64];
    __shared__ short Vs[64 * 64];
    const int t = threadIdx.x, l = t & 63, w = t >> 6;
    const int lo = l & 15, hi = l >> 4;
    const int lr = l >> 3, ls = l & 7;
    const int qtile = 15 - (int)blockIdx.x;   // heavy blocks first
    const int h = blockIdx.y, b = blockIdx.z;
    const int kvh = h >> 2;
    const size_t qbase  = (size_t)(b * 32 + h) * 2048 * 64;
    const size_t kbase  = (size_t)(b * 8 + kvh) * 2048 * 64;
    const size_t vtbase = (size_t)(b * 8 + kvh) * 64 * 2048;

    // Q fragments (B operand): lane provides Q[q = lo (local)][d-slice]
    short8 qf[2][2];
    #pragma unroll
    for (int g = 0; g < 2; ++g) {
        int qrow = qtile * 128 + w * 32 + g * 16 + lo;
        #pragma unroll
        for (int ks = 0; ks < 2; ++ks)
            qf[g][ks] = *(const short8*)(Qp + qbase + (size_t)qrow * 64 + (ks * 4 + hi) * 8);
    }

    const f32x4 z4 = {0.f, 0.f, 0.f, 0.f};
    float m_run[2] = {-1e30f, -1e30f};
    float l_run[2] = {0.f, 0.f};
    f32x4 oacc[2][4];
    #pragma unroll
    for (int g = 0; g < 2; ++g)
        #pragma unroll
        for (int nd = 0; nd < 4; ++nd) oacc[g][nd] = z4;

    const int nkt = 2 * qtile + 2;
    for (int kt = 0; kt < nkt; ++kt) {
        // stage K tile (rows k, cols d) and Vt tile (rows d, cols k), 8KB each
        #pragma unroll
        for (int j = 0; j < 2; ++j) {
            int g = w * 2 + j;
            int row = g * 8 + lr;
            int gs = ls ^ SW(row);
            async16(Ks + g * 512, Kp + kbase + (size_t)(kt * 64 + row) * 64 + gs * 8);
            async16(Vs + g * 512, Vt + vtbase + (size_t)row * 2048 + kt * 64 + gs * 8);
        }
        __syncthreads();

        // S^T = K Q^T with sigma row permutation
        f32x4 sacc[2][4];
        #pragma unroll
        for (int g = 0; g < 2; ++g)
            #pragma unroll
            for (int n = 0; n < 4; ++n) sacc[g][n] = z4;
        #pragma unroll
        for (int ks = 0; ks < 2; ++ks) {
            const int slot = ks * 4 + hi;
            #pragma unroll
            for (int n = 0; n < 4; ++n) {
                int krow = ((lo >> 2) << 3) + ((n & 1) << 2) + (lo & 3) + ((n >> 1) << 5);
                short8 kf = *(const short8*)(Ks + krow * 64 + ((slot ^ SW(krow)) << 3));
                sacc[0][n] = MFMA(kf, qf[0][ks], sacc[0][n]);
                sacc[1][n] = MFMA(kf, qf[1][ks], sacc[1][n]);
            }
        }

        // online softmax per group; lane owns q-row = lo, holds 16 k-slots
        short8 afr[2][2];
        #pragma unroll
        for (int g = 0; g < 2; ++g) {
            const int q = qtile * 128 + w * 32 + g * 16 + lo;
            float p[4][4];
            float pm = -1e30f;
            #pragma unroll
            for (int n = 0; n < 4; ++n)
                #pragma unroll
                for (int r = 0; r < 4; ++r) {
                    int k = kt * 64 + hi * 8 + ((n & 1) << 2) + r + ((n >> 1) << 5);
                    float sv = sacc[g][n][r] * 0.125f;
                    sv = (k > q) ? -1e30f : sv;
                    p[n][r] = sv;
                    pm = fmaxf(pm, sv);
                }
            pm = fmaxf(pm, __shfl_xor(pm, 16, 64));
            pm = fmaxf(pm, __shfl_xor(pm, 32, 64));
            float mn = fmaxf(m_run[g], pm);
            float al = __expf(m_run[g] - mn);
            m_run[g] = mn;
            float rsum = 0.f;
            #pragma unroll
            for (int n = 0; n < 4; ++n)
                #pragma unroll
                for (int r = 0; r < 4; ++r) {
                    float e = __expf(p[n][r] - mn);
                    p[n][r] = e;
                    rsum += e;
                }
            rsum += __shfl_xor(rsum, 16, 64);
            rsum += __shfl_xor(rsum, 32, 64);
            l_run[g] = l_run[g] * al + rsum;
            // rescale O accumulators: need al of q-row (hi*4+r)
            float alq[4];
            #pragma unroll
            for (int r = 0; r < 4; ++r)
                alq[r] = __shfl(al, (l & 48) | (hi * 4 + r), 64);
            #pragma unroll
            for (int nd = 0; nd < 4; ++nd) {
                oacc[g][nd][0] *= alq[0]; oacc[g][nd][1] *= alq[1];
                oacc[g][nd][2] *= alq[2]; oacc[g][nd][3] *= alq[3];
            }
            // pack P -> PV A-fragments (lane-local by construction)
            #pragma unroll
            for (int ks = 0; ks < 2; ++ks) {
                short8 a;
                a[0] = f2bs(p[2 * ks][0]);     a[1] = f2bs(p[2 * ks][1]);
                a[2] = f2bs(p[2 * ks][2]);     a[3] = f2bs(p[2 * ks][3]);
                a[4] = f2bs(p[2 * ks + 1][0]); a[5] = f2bs(p[2 * ks + 1][1]);
                a[6] = f2bs(p[2 * ks + 1][2]); a[7] = f2bs(p[2 * ks + 1][3]);
                afr[g][ks] = a;
            }
        }

        // O += P V  (B operand = Vt rows d, k contiguous)
        #pragma unroll
        for (int ks = 0; ks < 2; ++ks) {
            const int slot = ks * 4 + hi;
            #pragma unroll
            for (int nd = 0; nd < 4; ++nd) {
                int vrow = nd * 16 + lo;
                short8 vf = *(const short8*)(Vs + vrow * 64 + ((slot ^ SW(vrow)) << 3));
                oacc[0][nd] = MFMA(afr[0][ks], vf, oacc[0][nd]);
                oacc[1][nd] = MFMA(afr[1][ks], vf, oacc[1][nd]);
            }
        }
        __syncthreads();
    }

    // epilogue: write (b, s, h*64+d) bf16
    const size_t abase = (size_t)b * 2048 * 2048 + (size_t)h * 64;
    #pragma unroll
    for (int g = 0; g < 2; ++g) {
        float lq[4];
        #pragma unroll
        for (int r = 0; r < 4; ++r)
            lq[r] = __shfl(l_run[g], (l & 48) | (hi * 4 + r), 64);
        #pragma unroll
        for (int nd = 0; nd < 4; ++nd)
            #pragma unroll
            for (int r = 0; r < 4; ++r) {
                int s = qtile * 128 + w * 32 + g * 16 + hi * 4 + r;
                Ab[abase + (size_t)s * 2048 + nd * 16 + lo] = f2bs(oacc[g][nd][r] / lq[r]);
            }
    }
}

extern "C" void kernel_launch(void* const* d_in, const int* in_sizes, int n_in,
                              void* d_out, int out_size, void* d_ws, size_t ws_size,
                              hipStream_t stream)
{
    const float* x  = (const float*)d_in[0];
    const float* Wq = (const float*)d_in[1];
    const float* Wk = (const float*)d_in[2];
    const float* Wv = (const float*)d_in[3];
    const float* Wo = (const float*)d_in[4];
    const float* rc = (const float*)d_in[5];
    const float* rs = (const float*)d_in[6];
    float* out = (float*)d_out;
    char* ws = (char*)d_ws;

    size_t off = 0;
    short* x_bf  = (short*)(ws + off); off += (size_t)4096 * 2048 * 2;
    short* Wq_t  = (short*)(ws + off); off += (size_t)2048 * 2048 * 2;
    short* Wkv_t = (short*)(ws + off); off += (size_t)1024 * 2048 * 2;
    short* Wo_t  = (short*)(ws + off); off += (size_t)2048 * 2048 * 2;
    short* Qp    = (short*)(ws + off); off += (size_t)2 * 32 * 2048 * 64 * 2;
    short* Kp    = (short*)(ws + off); off += (size_t)2 * 8 * 2048 * 64 * 2;
    short* Vtb   = (short*)(ws + off); off += (size_t)2 * 8 * 64 * 2048 * 2;
    short* Ab    = (short*)(ws + off); off += (size_t)4096 * 2048 * 2;
    if (off > ws_size) return;

    cast_bf16_k<<<8192, 256, 0, stream>>>(x, x_bf, 2097152);
    transpose_cast_k<<<dim3(64, 64), dim3(32, 8), 0, stream>>>(Wq, Wq_t, 2048, 2048);
    transpose_cast_k<<<dim3(16, 64), dim3(32, 8), 0, stream>>>(Wk, Wkv_t, 2048, 512);
    transpose_cast_k<<<dim3(16, 64), dim3(32, 8), 0, stream>>>(Wv, Wkv_t + (size_t)512 * 2048, 2048, 512);
    transpose_cast_k<<<dim3(64, 64), dim3(32, 8), 0, stream>>>(Wo, Wo_t, 2048, 2048);

    // Q: rope+pack (32 heads). KV merged: K rope+pack (8 heads) + V transposed pack.
    gemm_bt<<<dim3(32, 16), 256, 0, stream>>>(x_bf, Wq_t, nullptr, Qp, nullptr, rc, rs, 4096, 2048, 2048, 1, 32);
    gemm_bt<<<dim3(32, 8),  256, 0, stream>>>(x_bf, Wkv_t, nullptr, Kp, Vtb, rc, rs, 4096, 1024, 2048, 3, 8);

    attn_k<<<dim3(16, 32, 2), 256, 0, stream>>>(Qp, Kp, Vtb, Ab);

    gemm_bt<<<dim3(32, 16), 256, 0, stream>>>(Ab, Wo_t, out, nullptr, nullptr, nullptr, nullptr, 4096, 2048, 2048, 0, 0);
}

// Round 3
// 216.876 us; speedup vs baseline: 2.2872x; 1.4211x over previous
//
#include <hip/hip_runtime.h>
#include <hip/hip_bf16.h>

typedef __attribute__((ext_vector_type(8))) short short8;
typedef __attribute__((ext_vector_type(4))) short short4v;
typedef __attribute__((ext_vector_type(4))) float f32x4;

#define MFMA(A,B,C) __builtin_amdgcn_mfma_f32_16x16x32_bf16(A,B,C,0,0,0)
// swizzle: 3 bits from row bits {0,1,3} so fragment reads spread 8 bank-quads
#define SW(row) ((((row) & 3)) | (((row) >> 1) & 4))
#define SCL 0.18033688f  // 0.125 * log2(e): folded into Q so scores are base-2

__device__ __forceinline__ short f2bs(float f) {
    __hip_bfloat16 h = __float2bfloat16(f);
    union { __hip_bfloat16 h; short s; } u; u.h = h; return u.s;
}

__device__ __forceinline__ float exp2v(float x) {  // bare v_exp_f32 (D = 2^S0)
    float r; asm("v_exp_f32 %0, %1" : "=v"(r) : "v"(x)); return r;
}

__device__ __forceinline__ void async16(void* lds, const void* g) {
    __builtin_amdgcn_global_load_lds(
        (const __attribute__((address_space(1))) unsigned int*)g,
        (__attribute__((address_space(3))) unsigned int*)lds, 16, 0, 0);
}

// ---------------- cast fp32 -> bf16, vectorized x4 ----------------
__global__ __launch_bounds__(256) void cast_bf16_k(const float* __restrict__ X,
                                                   short* __restrict__ Y, int n4) {
    int i = blockIdx.x * 256 + threadIdx.x;
    if (i >= n4) return;
    const float4 v = *(const float4*)(X + (size_t)i * 4);
    short4v o;
    o.x = f2bs(v.x); o.y = f2bs(v.y); o.z = f2bs(v.z); o.w = f2bs(v.w);
    *(short4v*)(Y + (size_t)i * 4) = o;
}

// ---------------- transpose + cast: Wt[n][k] = W[k][n] ----------------
__global__ __launch_bounds__(256) void transpose_cast_k(const float* __restrict__ W,
                                                        short* __restrict__ Wt, int K, int N) {
    __shared__ float tile[32][33];
    int n0 = blockIdx.x * 32, k0 = blockIdx.y * 32;
    int tx = threadIdx.x, ty = threadIdx.y;
    #pragma unroll
    for (int i = 0; i < 32; i += 8)
        tile[ty + i][tx] = W[(size_t)(k0 + ty + i) * N + n0 + tx];
    __syncthreads();
    #pragma unroll
    for (int i = 0; i < 32; i += 8)
        Wt[(size_t)(n0 + ty + i) * K + k0 + tx] = f2bs(tile[tx][ty + i]);
}

// ---------------- GEMM: C = A(M,K) @ Bt(N,K)^T, bf16 in, fp32 acc ----------------
// epi 0: fp32 C row-major (O projection)
// epi 4: merged QKV: cols [0,2048) Q rope*SCL pack; [2048,2560) K rope pack;
//        [2560,3072) V transposed pack (b,8,64,2048)
__global__ __launch_bounds__(256) void gemm_bt(
    const short* __restrict__ A, const short* __restrict__ Bt,
    float* __restrict__ Cf, short* __restrict__ Cq, short* __restrict__ Ck,
    short* __restrict__ Cv,
    const float* __restrict__ rc, const float* __restrict__ rs,
    int M, int N, int K, int epi)
{
    __shared__ short As[128 * 64];
    __shared__ short Bs[128 * 64];
    const int t = threadIdx.x;
    const int l = t & 63, w = t >> 6;
    const int lo = l & 15, hi = l >> 4;
    const int wm = w >> 1, wn = w & 1;
    const int tm = blockIdx.x * 128, tn = blockIdx.y * 128;
    const int lr = l >> 3, ls = l & 7;

    const f32x4 z4 = {0.f, 0.f, 0.f, 0.f};
    f32x4 acc[4][4];
    #pragma unroll
    for (int m = 0; m < 4; ++m)
        #pragma unroll
        for (int n = 0; n < 4; ++n) acc[m][n] = z4;

    for (int k0 = 0; k0 < K; k0 += 64) {
        #pragma unroll
        for (int i = 0; i < 4; ++i) {
            int g = w * 4 + i;
            int row = g * 8 + lr;
            int gs = ls ^ SW(row);
            async16(As + g * 512, A + (size_t)(tm + row) * K + k0 + gs * 8);
            async16(Bs + g * 512, Bt + (size_t)(tn + row) * K + k0 + gs * 8);
        }
        __syncthreads();
        #pragma unroll
        for (int ks = 0; ks < 2; ++ks) {
            const int slot = ks * 4 + hi;
            short8 af[4], bfr[4];
            #pragma unroll
            for (int m = 0; m < 4; ++m) {
                int row = wm * 64 + m * 16 + lo;
                af[m] = *(const short8*)(As + row * 64 + ((slot ^ SW(row)) << 3));
            }
            #pragma unroll
            for (int n = 0; n < 4; ++n) {
                int row = wn * 64 + n * 16 + lo;
                bfr[n] = *(const short8*)(Bs + row * 64 + ((slot ^ SW(row)) << 3));
            }
            #pragma unroll
            for (int m = 0; m < 4; ++m)
                #pragma unroll
                for (int n = 0; n < 4; ++n)
                    acc[m][n] = MFMA(af[m], bfr[n], acc[m][n]);
        }
        __syncthreads();
    }

    if (epi == 0) {
        #pragma unroll
        for (int m = 0; m < 4; ++m)
            #pragma unroll
            for (int r = 0; r < 4; ++r) {
                int row = tm + wm * 64 + m * 16 + hi * 4 + r;
                #pragma unroll
                for (int n = 0; n < 4; ++n) {
                    int col = tn + wn * 64 + n * 16 + lo;
                    Cf[(size_t)row * N + col] = acc[m][n][r];
                }
            }
    } else {
        const int ctn = tn + wn * 64;  // 64-col strip base; strip stays in one region
        if (ctn < 2048) {              // ---- Q: rope + fold softmax scale ----
            #pragma unroll
            for (int m = 0; m < 4; ++m)
                #pragma unroll
                for (int r = 0; r < 4; ++r) {
                    int row = tm + wm * 64 + m * 16 + hi * 4 + r;
                    int b = row >> 11, s = row & 2047;
                    #pragma unroll
                    for (int n = 0; n < 2; ++n) {
                        int col = ctn + n * 16 + lo;
                        int h = col >> 6, d = col & 63;  // d < 32
                        float x1 = acc[m][n][r], x2 = acc[m][n + 2][r];
                        float c = rc[s * 32 + d], sn = rs[s * 32 + d];
                        size_t base = (((size_t)b * 32 + h) * 2048 + s) * 64;
                        Cq[base + d]      = f2bs((x1 * c - x2 * sn) * SCL);
                        Cq[base + d + 32] = f2bs((x1 * sn + x2 * c) * SCL);
                    }
                }
        } else if (ctn < 2560) {       // ---- K: rope pack ----
            #pragma unroll
            for (int m = 0; m < 4; ++m)
                #pragma unroll
                for (int r = 0; r < 4; ++r) {
                    int row = tm + wm * 64 + m * 16 + hi * 4 + r;
                    int b = row >> 11, s = row & 2047;
                    #pragma unroll
                    for (int n = 0; n < 2; ++n) {
                        int col = ctn - 2048 + n * 16 + lo;
                        int h = col >> 6, d = col & 63;  // d < 32
                        float x1 = acc[m][n][r], x2 = acc[m][n + 2][r];
                        float c = rc[s * 32 + d], sn = rs[s * 32 + d];
                        size_t base = (((size_t)b * 8 + h) * 2048 + s) * 64;
                        Ck[base + d]      = f2bs(x1 * c - x2 * sn);
                        Ck[base + d + 32] = f2bs(x1 * sn + x2 * c);
                    }
                }
        } else {                       // ---- V: transposed pack (b,8,64,2048) ----
            #pragma unroll
            for (int m = 0; m < 4; ++m)
                #pragma unroll
                for (int r = 0; r < 4; ++r) {
                    int row = tm + wm * 64 + m * 16 + hi * 4 + r;
                    int b = row >> 11, s = row & 2047;
                    #pragma unroll
                    for (int n = 0; n < 4; ++n) {
                        int col = ctn - 2560 + n * 16 + lo;
                        int h = col >> 6, d = col & 63;
                        Cv[(((size_t)b * 8 + h) * 64 + d) * 2048 + s] = f2bs(acc[m][n][r]);
                    }
                }
        }
    }
}

// ---------------- flash attention, pair-balanced ----------------
// block = (pair, h, b); each block does qtile=pair then qtile=15-pair -> 34 k-steps
// for every block. 4 waves x 32 q-rows. Double-buffered K/V staging with prefetch.
// Scores arrive pre-scaled by 0.125*log2e (folded into Q) -> softmax in base 2.
__global__ __launch_bounds__(256) void attn_k(
    const short* __restrict__ Qp, const short* __restrict__ Kp, const short* __restrict__ Vt,
    short* __restrict__ Ab)
{
    __shared__ short KV[2][8192];  // [buf][ K:0..4095 | V:4096..8191 ], 32 KB
    const int t = threadIdx.x, l = t & 63, w = t >> 6;
    const int lo = l & 15, hi = l >> 4;
    const int lr = l >> 3, ls = l & 7;
    const int pair = blockIdx.x;   // 0..7
    const int h = blockIdx.y, b = blockIdx.z;
    const int kvh = h >> 2;
    const size_t qbase  = (size_t)(b * 32 + h) * 2048 * 64;
    const size_t kbase  = (size_t)(b * 8 + kvh) * 2048 * 64;
    const size_t vtbase = (size_t)(b * 8 + kvh) * 64 * 2048;
    const size_t abase  = (size_t)b * 2048 * 2048 + (size_t)h * 64;

    for (int halfq = 0; halfq < 2; ++halfq) {
        const int qtile = halfq ? 15 - pair : pair;
        const int nkt = 2 * qtile + 2;

        short8 qf[2][2];
        #pragma unroll
        for (int g = 0; g < 2; ++g) {
            int qrow = qtile * 128 + w * 32 + g * 16 + lo;
            #pragma unroll
            for (int ks = 0; ks < 2; ++ks)
                qf[g][ks] = *(const short8*)(Qp + qbase + (size_t)qrow * 64 + (ks * 4 + hi) * 8);
        }

        const f32x4 z4 = {0.f, 0.f, 0.f, 0.f};
        float m_run[2] = {-3e38f, -3e38f};
        float l_run[2] = {0.f, 0.f};
        f32x4 oacc[2][4];
        #pragma unroll
        for (int g = 0; g < 2; ++g)
            #pragma unroll
            for (int nd = 0; nd < 4; ++nd) oacc[g][nd] = z4;

        // prologue: stage kt=0 into buf 0
        #pragma unroll
        for (int j = 0; j < 2; ++j) {
            int g8 = w * 2 + j;
            int row = g8 * 8 + lr;
            int gs = ls ^ SW(row);
            async16(&KV[0][g8 * 512],        Kp + kbase + (size_t)row * 64 + gs * 8);
            async16(&KV[0][4096 + g8 * 512], Vt + vtbase + (size_t)row * 2048 + gs * 8);
        }
        __syncthreads();

        int cur = 0;
        for (int kt = 0; kt < nkt; ++kt) {
            // prefetch next tile into other buffer (overlaps with compute below)
            if (kt + 1 < nkt) {
                #pragma unroll
                for (int j = 0; j < 2; ++j) {
                    int g8 = w * 2 + j;
                    int row = g8 * 8 + lr;
                    int gs = ls ^ SW(row);
                    async16(&KV[cur ^ 1][g8 * 512],
                            Kp + kbase + (size_t)((kt + 1) * 64 + row) * 64 + gs * 8);
                    async16(&KV[cur ^ 1][4096 + g8 * 512],
                            Vt + vtbase + (size_t)row * 2048 + (kt + 1) * 64 + gs * 8);
                }
            }

            const short* Ks = &KV[cur][0];
            const short* Vs = &KV[cur][4096];

            // S^T = K Q^T with sigma row permutation (P lands as PV A-fragment)
            f32x4 sacc[2][4];
            #pragma unroll
            for (int g = 0; g < 2; ++g)
                #pragma unroll
                for (int n = 0; n < 4; ++n) sacc[g][n] = z4;
            __builtin_amdgcn_s_setprio(1);
            #pragma unroll
            for (int ks = 0; ks < 2; ++ks) {
                const int slot = ks * 4 + hi;
                #pragma unroll
                for (int n = 0; n < 4; ++n) {
                    const int krow = ((lo >> 2) << 3) + ((n & 1) << 2) + (lo & 3) + ((n >> 1) << 5);
                    short8 kf = *(const short8*)(Ks + krow * 64 + ((slot ^ SW(krow)) << 3));
                    sacc[0][n] = MFMA(kf, qf[0][ks], sacc[0][n]);
                    sacc[1][n] = MFMA(kf, qf[1][ks], sacc[1][n]);
                }
            }
            __builtin_amdgcn_s_setprio(0);

            short8 afr[2][2];
            #pragma unroll
            for (int g = 0; g < 2; ++g) {
                const int qmin = qtile * 128 + w * 32 + g * 16;
                const int q = qmin + lo;
                float p[4][4];
                float pm = -3e38f;
                if (kt * 64 + 63 > qmin) {  // diagonal tile: apply causal mask
                    #pragma unroll
                    for (int n = 0; n < 4; ++n)
                        #pragma unroll
                        for (int r = 0; r < 4; ++r) {
                            int k = kt * 64 + hi * 8 + ((n & 1) << 2) + r + ((n >> 1) << 5);
                            float sv = (k > q) ? -3e38f : sacc[g][n][r];
                            p[n][r] = sv;
                            pm = fmaxf(pm, sv);
                        }
                } else {
                    #pragma unroll
                    for (int n = 0; n < 4; ++n)
                        #pragma unroll
                        for (int r = 0; r < 4; ++r) {
                            p[n][r] = sacc[g][n][r];
                            pm = fmaxf(pm, p[n][r]);
                        }
                }
                pm = fmaxf(pm, __shfl_xor(pm, 16, 64));
                pm = fmaxf(pm, __shfl_xor(pm, 32, 64));
                if (!__all(pm <= m_run[g] + 8.f)) {  // defer-max: rescale rarely
                    float mn = fmaxf(m_run[g], pm);
                    float al = exp2v(m_run[g] - mn);
                    m_run[g] = mn;
                    l_run[g] *= al;
                    float alq[4];
                    #pragma unroll
                    for (int r = 0; r < 4; ++r)
                        alq[r] = __shfl(al, (l & 48) | (hi * 4 + r), 64);
                    #pragma unroll
                    for (int nd = 0; nd < 4; ++nd) {
                        oacc[g][nd][0] *= alq[0]; oacc[g][nd][1] *= alq[1];
                        oacc[g][nd][2] *= alq[2]; oacc[g][nd][3] *= alq[3];
                    }
                }
                float rsum = 0.f;
                #pragma unroll
                for (int n = 0; n < 4; ++n)
                    #pragma unroll
                    for (int r = 0; r < 4; ++r) {
                        float e = exp2v(p[n][r] - m_run[g]);
                        p[n][r] = e;
                        rsum += e;
                    }
                rsum += __shfl_xor(rsum, 16, 64);
                rsum += __shfl_xor(rsum, 32, 64);
                l_run[g] += rsum;
                #pragma unroll
                for (int ks = 0; ks < 2; ++ks) {
                    short8 a;
                    a[0] = f2bs(p[2 * ks][0]);     a[1] = f2bs(p[2 * ks][1]);
                    a[2] = f2bs(p[2 * ks][2]);     a[3] = f2bs(p[2 * ks][3]);
                    a[4] = f2bs(p[2 * ks + 1][0]); a[5] = f2bs(p[2 * ks + 1][1]);
                    a[6] = f2bs(p[2 * ks + 1][2]); a[7] = f2bs(p[2 * ks + 1][3]);
                    afr[g][ks] = a;
                }
            }

            // O += P V
            __builtin_amdgcn_s_setprio(1);
            #pragma unroll
            for (int ks = 0; ks < 2; ++ks) {
                const int slot = ks * 4 + hi;
                #pragma unroll
                for (int nd = 0; nd < 4; ++nd) {
                    const int vrow = nd * 16 + lo;
                    short8 vf = *(const short8*)(Vs + vrow * 64 + ((slot ^ SW(vrow)) << 3));
                    oacc[0][nd] = MFMA(afr[0][ks], vf, oacc[0][nd]);
                    oacc[1][nd] = MFMA(afr[1][ks], vf, oacc[1][nd]);
                }
            }
            __builtin_amdgcn_s_setprio(0);

            __syncthreads();   // drains prefetch vmcnt + releases buf[cur] for overwrite
            cur ^= 1;
        }

        // epilogue for this qtile
        #pragma unroll
        for (int g = 0; g < 2; ++g) {
            float rl[4];
            #pragma unroll
            for (int r = 0; r < 4; ++r)
                rl[r] = 1.0f / __shfl(l_run[g], (l & 48) | (hi * 4 + r), 64);
            #pragma unroll
            for (int nd = 0; nd < 4; ++nd)
                #pragma unroll
                for (int r = 0; r < 4; ++r) {
                    int s = qtile * 128 + w * 32 + g * 16 + hi * 4 + r;
                    Ab[abase + (size_t)s * 2048 + nd * 16 + lo] = f2bs(oacc[g][nd][r] * rl[r]);
                }
        }
    }
}

extern "C" void kernel_launch(void* const* d_in, const int* in_sizes, int n_in,
                              void* d_out, int out_size, void* d_ws, size_t ws_size,
                              hipStream_t stream)
{
    const float* x  = (const float*)d_in[0];
    const float* Wq = (const float*)d_in[1];
    const float* Wk = (const float*)d_in[2];
    const float* Wv = (const float*)d_in[3];
    const float* Wo = (const float*)d_in[4];
    const float* rc = (const float*)d_in[5];
    const float* rs = (const float*)d_in[6];
    float* out = (float*)d_out;
    char* ws = (char*)d_ws;

    size_t off = 0;
    short* x_bf   = (short*)(ws + off); off += (size_t)4096 * 2048 * 2;
    short* Wqkv_t = (short*)(ws + off); off += (size_t)3072 * 2048 * 2;
    short* Wo_t   = (short*)(ws + off); off += (size_t)2048 * 2048 * 2;
    short* Qp     = (short*)(ws + off); off += (size_t)2 * 32 * 2048 * 64 * 2;
    short* Kp     = (short*)(ws + off); off += (size_t)2 * 8 * 2048 * 64 * 2;
    short* Vtb    = (short*)(ws + off); off += (size_t)2 * 8 * 64 * 2048 * 2;
    short* Ab     = (short*)(ws + off); off += (size_t)4096 * 2048 * 2;
    if (off > ws_size) return;

    cast_bf16_k<<<8192, 256, 0, stream>>>(x, x_bf, 2097152);
    transpose_cast_k<<<dim3(64, 64), dim3(32, 8), 0, stream>>>(Wq, Wqkv_t, 2048, 2048);
    transpose_cast_k<<<dim3(16, 64), dim3(32, 8), 0, stream>>>(Wk, Wqkv_t + (size_t)2048 * 2048, 2048, 512);
    transpose_cast_k<<<dim3(16, 64), dim3(32, 8), 0, stream>>>(Wv, Wqkv_t + (size_t)2560 * 2048, 2048, 512);
    transpose_cast_k<<<dim3(64, 64), dim3(32, 8), 0, stream>>>(Wo, Wo_t, 2048, 2048);

    // merged QKV projection: Q rope*SCL pack | K rope pack | V transpose pack
    gemm_bt<<<dim3(32, 24), 256, 0, stream>>>(x_bf, Wqkv_t, nullptr, Qp, Kp, Vtb,
                                              rc, rs, 4096, 3072, 2048, 4);

    attn_k<<<dim3(8, 32, 2), 256, 0, stream>>>(Qp, Kp, Vtb, Ab);

    gemm_bt<<<dim3(32, 16), 256, 0, stream>>>(Ab, Wo_t, out, nullptr, nullptr, nullptr,
                                              nullptr, nullptr, 4096, 2048, 2048, 0);
}

// Round 4
// 194.789 us; speedup vs baseline: 2.5466x; 1.1134x over previous
//
#include <hip/hip_runtime.h>
#include <hip/hip_bf16.h>

typedef __attribute__((ext_vector_type(8))) short short8;
typedef __attribute__((ext_vector_type(4))) short short4v;
typedef __attribute__((ext_vector_type(4))) float f32x4;

#define MFMA(A,B,C) __builtin_amdgcn_mfma_f32_16x16x32_bf16(A,B,C,0,0,0)
// swizzle: 3 bits from row bits {0,1,3} so fragment reads spread 8 bank-quads
#define SW(row) ((((row) & 3)) | (((row) >> 1) & 4))
#define SCL 0.18033688f  // 0.125 * log2(e): folded into Q so scores are base-2

__device__ __forceinline__ short f2bs(float f) {
    __hip_bfloat16 h = __float2bfloat16(f);
    union { __hip_bfloat16 h; short s; } u; u.h = h; return u.s;
}

__device__ __forceinline__ float exp2v(float x) {  // bare v_exp_f32 (D = 2^S0)
    float r; asm("v_exp_f32 %0, %1" : "=v"(r) : "v"(x)); return r;
}

__device__ __forceinline__ void async16(void* lds, const void* g) {
    __builtin_amdgcn_global_load_lds(
        (const __attribute__((address_space(1))) unsigned int*)g,
        (__attribute__((address_space(3))) unsigned int*)lds, 16, 0, 0);
}

// ---------------- cast fp32 -> bf16, vectorized x4 ----------------
__global__ __launch_bounds__(256) void cast_bf16_k(const float* __restrict__ X,
                                                   short* __restrict__ Y, int n4) {
    int i = blockIdx.x * 256 + threadIdx.x;
    if (i >= n4) return;
    const float4 v = *(const float4*)(X + (size_t)i * 4);
    short4v o;
    o.x = f2bs(v.x); o.y = f2bs(v.y); o.z = f2bs(v.z); o.w = f2bs(v.w);
    *(short4v*)(Y + (size_t)i * 4) = o;
}

// ---------------- transpose + cast: Wt[n][k] = W[k][n] ----------------
__global__ __launch_bounds__(256) void transpose_cast_k(const float* __restrict__ W,
                                                        short* __restrict__ Wt, int K, int N) {
    __shared__ float tile[32][33];
    int n0 = blockIdx.x * 32, k0 = blockIdx.y * 32;
    int tx = threadIdx.x, ty = threadIdx.y;
    #pragma unroll
    for (int i = 0; i < 32; i += 8)
        tile[ty + i][tx] = W[(size_t)(k0 + ty + i) * N + n0 + tx];
    __syncthreads();
    #pragma unroll
    for (int i = 0; i < 32; i += 8)
        Wt[(size_t)(n0 + ty + i) * K + k0 + tx] = f2bs(tile[tx][ty + i]);
}

// ---------------- GEMM: C = A(M,K) @ Bt(N,K)^T ----------------
// 256x128 tile, BK=64, 8 waves (4x2), wave tile 64x64. Ring-of-3 LDS K-tile
// buffers (144KB dynamic), counted vmcnt(6): prefetched tile's loads stay in
// flight across the per-iteration raw s_barrier (no vmcnt(0) drain).
// epi 0: fp32 C row-major (O projection)
// epi 4: merged QKV: cols [0,2048) Q rope*SCL pack; [2048,2560) K rope pack;
//        [2560,3072) V transposed pack (b,8,64,2048)
__global__ __launch_bounds__(512, 2) void gemm_k(
    const short* __restrict__ A, const short* __restrict__ Bt,
    float* __restrict__ Cf, short* __restrict__ Cq, short* __restrict__ Ck,
    short* __restrict__ Cv,
    const float* __restrict__ rc, const float* __restrict__ rs,
    int M, int N, int K, int epi)
{
    extern __shared__ short lds[];   // 3 bufs x (A 256x64 | B 128x64) = 3 x 24576 shorts
    const int t = threadIdx.x;
    const int l = t & 63, w = t >> 6;        // 8 waves
    const int lo = l & 15, hi = l >> 4;
    const int wm = w >> 1, wn = w & 1;       // 4 x 2 wave grid
    const int tm = blockIdx.x * 256, tn = blockIdx.y * 128;
    const int lr = l >> 3, ls = l & 7;

    const f32x4 z4 = {0.f, 0.f, 0.f, 0.f};
    f32x4 acc[4][4];
    #pragma unroll
    for (int m = 0; m < 4; ++m)
        #pragma unroll
        for (int n = 0; n < 4; ++n) acc[m][n] = z4;

    auto stage = [&](int kt, int buf) {
        const size_t ko = (size_t)kt * 64;
        short* Abuf = lds + buf * 24576;
        short* Bbuf = Abuf + 16384;
        #pragma unroll
        for (int j = 0; j < 4; ++j) {        // A: 256 rows
            int g = w * 4 + j;
            int row = g * 8 + lr;
            int gs = ls ^ SW(row);
            async16(Abuf + g * 512, A + (size_t)(tm + row) * K + ko + gs * 8);
        }
        #pragma unroll
        for (int j = 0; j < 2; ++j) {        // B: 128 rows
            int g = w * 2 + j;
            int row = g * 8 + lr;
            int gs = ls ^ SW(row);
            async16(Bbuf + g * 512, Bt + (size_t)(tn + row) * K + ko + gs * 8);
        }
    };

    const int nkt = K >> 6;   // 32
    stage(0, 0);
    if (nkt > 1) stage(1, 1);

    int buf = 0;
    for (int kt = 0; kt < nkt; ++kt) {
        if (kt + 1 < nkt) asm volatile("s_waitcnt vmcnt(6)" ::: "memory");
        else              asm volatile("s_waitcnt vmcnt(0)" ::: "memory");
        __builtin_amdgcn_s_barrier();
        if (kt + 2 < nkt) {
            int tb = buf - 1; if (tb < 0) tb = 2;   // (buf+2)%3
            stage(kt + 2, tb);
        }
        const short* Ab_ = lds + buf * 24576;
        const short* Bb_ = Ab_ + 16384;
        #pragma unroll
        for (int ks = 0; ks < 2; ++ks) {
            const int slot = ks * 4 + hi;
            short8 af[4], bfr[4];
            #pragma unroll
            for (int m = 0; m < 4; ++m) {
                int row = wm * 64 + m * 16 + lo;
                af[m] = *(const short8*)(Ab_ + row * 64 + ((slot ^ SW(row)) << 3));
            }
            #pragma unroll
            for (int n = 0; n < 4; ++n) {
                int row = wn * 64 + n * 16 + lo;
                bfr[n] = *(const short8*)(Bb_ + row * 64 + ((slot ^ SW(row)) << 3));
            }
            __builtin_amdgcn_s_setprio(1);
            #pragma unroll
            for (int m = 0; m < 4; ++m)
                #pragma unroll
                for (int n = 0; n < 4; ++n)
                    acc[m][n] = MFMA(af[m], bfr[n], acc[m][n]);
            __builtin_amdgcn_s_setprio(0);
        }
        buf = (buf == 2) ? 0 : buf + 1;
    }

    if (epi == 0) {
        #pragma unroll
        for (int m = 0; m < 4; ++m)
            #pragma unroll
            for (int r = 0; r < 4; ++r) {
                int row = tm + wm * 64 + m * 16 + hi * 4 + r;
                #pragma unroll
                for (int n = 0; n < 4; ++n) {
                    int col = tn + wn * 64 + n * 16 + lo;
                    Cf[(size_t)row * N + col] = acc[m][n][r];
                }
            }
    } else {
        const int ctn = tn + wn * 64;  // 64-col strip base; strip stays in one region
        if (ctn < 2048) {              // ---- Q: rope + fold softmax scale ----
            #pragma unroll
            for (int m = 0; m < 4; ++m)
                #pragma unroll
                for (int r = 0; r < 4; ++r) {
                    int row = tm + wm * 64 + m * 16 + hi * 4 + r;
                    int b = row >> 11, s = row & 2047;
                    #pragma unroll
                    for (int n = 0; n < 2; ++n) {
                        int col = ctn + n * 16 + lo;
                        int h = col >> 6, d = col & 63;  // d < 32
                        float x1 = acc[m][n][r], x2 = acc[m][n + 2][r];
                        float c = rc[s * 32 + d], sn = rs[s * 32 + d];
                        size_t base = (((size_t)b * 32 + h) * 2048 + s) * 64;
                        Cq[base + d]      = f2bs((x1 * c - x2 * sn) * SCL);
                        Cq[base + d + 32] = f2bs((x1 * sn + x2 * c) * SCL);
                    }
                }
        } else if (ctn < 2560) {       // ---- K: rope pack ----
            #pragma unroll
            for (int m = 0; m < 4; ++m)
                #pragma unroll
                for (int r = 0; r < 4; ++r) {
                    int row = tm + wm * 64 + m * 16 + hi * 4 + r;
                    int b = row >> 11, s = row & 2047;
                    #pragma unroll
                    for (int n = 0; n < 2; ++n) {
                        int col = ctn - 2048 + n * 16 + lo;
                        int h = col >> 6, d = col & 63;  // d < 32
                        float x1 = acc[m][n][r], x2 = acc[m][n + 2][r];
                        float c = rc[s * 32 + d], sn = rs[s * 32 + d];
                        size_t base = (((size_t)b * 8 + h) * 2048 + s) * 64;
                        Ck[base + d]      = f2bs(x1 * c - x2 * sn);
                        Ck[base + d + 32] = f2bs(x1 * sn + x2 * c);
                    }
                }
        } else {                       // ---- V: transposed pack (b,8,64,2048) ----
            #pragma unroll
            for (int m = 0; m < 4; ++m)
                #pragma unroll
                for (int r = 0; r < 4; ++r) {
                    int row = tm + wm * 64 + m * 16 + hi * 4 + r;
                    int b = row >> 11, s = row & 2047;
                    #pragma unroll
                    for (int n = 0; n < 4; ++n) {
                        int col = ctn - 2560 + n * 16 + lo;
                        int h = col >> 6, d = col & 63;
                        Cv[(((size_t)b * 8 + h) * 64 + d) * 2048 + s] = f2bs(acc[m][n][r]);
                    }
                }
        }
    }
}

// ---------------- flash attention, pair-balanced ----------------
// block = (pair, h, b); each block does qtile=pair then qtile=15-pair -> 34 k-steps
// for every block. 4 waves x 32 q-rows. Double-buffered K/V staging with prefetch.
// Scores arrive pre-scaled by 0.125*log2e (folded into Q) -> softmax in base 2.
__global__ __launch_bounds__(256) void attn_k(
    const short* __restrict__ Qp, const short* __restrict__ Kp, const short* __restrict__ Vt,
    short* __restrict__ Ab)
{
    __shared__ short KV[2][8192];  // [buf][ K:0..4095 | V:4096..8191 ], 32 KB
    const int t = threadIdx.x, l = t & 63, w = t >> 6;
    const int lo = l & 15, hi = l >> 4;
    const int lr = l >> 3, ls = l & 7;
    const int pair = blockIdx.x;   // 0..7
    const int h = blockIdx.y, b = blockIdx.z;
    const int kvh = h >> 2;
    const size_t qbase  = (size_t)(b * 32 + h) * 2048 * 64;
    const size_t kbase  = (size_t)(b * 8 + kvh) * 2048 * 64;
    const size_t vtbase = (size_t)(b * 8 + kvh) * 64 * 2048;
    const size_t abase  = (size_t)b * 2048 * 2048 + (size_t)h * 64;

    for (int halfq = 0; halfq < 2; ++halfq) {
        const int qtile = halfq ? 15 - pair : pair;
        const int nkt = 2 * qtile + 2;

        short8 qf[2][2];
        #pragma unroll
        for (int g = 0; g < 2; ++g) {
            int qrow = qtile * 128 + w * 32 + g * 16 + lo;
            #pragma unroll
            for (int ks = 0; ks < 2; ++ks)
                qf[g][ks] = *(const short8*)(Qp + qbase + (size_t)qrow * 64 + (ks * 4 + hi) * 8);
        }

        const f32x4 z4 = {0.f, 0.f, 0.f, 0.f};
        float m_run[2] = {-3e38f, -3e38f};
        float l_run[2] = {0.f, 0.f};
        f32x4 oacc[2][4];
        #pragma unroll
        for (int g = 0; g < 2; ++g)
            #pragma unroll
            for (int nd = 0; nd < 4; ++nd) oacc[g][nd] = z4;

        // prologue: stage kt=0 into buf 0
        #pragma unroll
        for (int j = 0; j < 2; ++j) {
            int g8 = w * 2 + j;
            int row = g8 * 8 + lr;
            int gs = ls ^ SW(row);
            async16(&KV[0][g8 * 512],        Kp + kbase + (size_t)row * 64 + gs * 8);
            async16(&KV[0][4096 + g8 * 512], Vt + vtbase + (size_t)row * 2048 + gs * 8);
        }
        __syncthreads();

        int cur = 0;
        for (int kt = 0; kt < nkt; ++kt) {
            // prefetch next tile into other buffer (overlaps with compute below)
            if (kt + 1 < nkt) {
                #pragma unroll
                for (int j = 0; j < 2; ++j) {
                    int g8 = w * 2 + j;
                    int row = g8 * 8 + lr;
                    int gs = ls ^ SW(row);
                    async16(&KV[cur ^ 1][g8 * 512],
                            Kp + kbase + (size_t)((kt + 1) * 64 + row) * 64 + gs * 8);
                    async16(&KV[cur ^ 1][4096 + g8 * 512],
                            Vt + vtbase + (size_t)row * 2048 + (kt + 1) * 64 + gs * 8);
                }
            }

            const short* Ks = &KV[cur][0];
            const short* Vs = &KV[cur][4096];

            // S^T = K Q^T with sigma row permutation (P lands as PV A-fragment)
            f32x4 sacc[2][4];
            #pragma unroll
            for (int g = 0; g < 2; ++g)
                #pragma unroll
                for (int n = 0; n < 4; ++n) sacc[g][n] = z4;
            __builtin_amdgcn_s_setprio(1);
            #pragma unroll
            for (int ks = 0; ks < 2; ++ks) {
                const int slot = ks * 4 + hi;
                #pragma unroll
                for (int n = 0; n < 4; ++n) {
                    const int krow = ((lo >> 2) << 3) + ((n & 1) << 2) + (lo & 3) + ((n >> 1) << 5);
                    short8 kf = *(const short8*)(Ks + krow * 64 + ((slot ^ SW(krow)) << 3));
                    sacc[0][n] = MFMA(kf, qf[0][ks], sacc[0][n]);
                    sacc[1][n] = MFMA(kf, qf[1][ks], sacc[1][n]);
                }
            }
            __builtin_amdgcn_s_setprio(0);

            short8 afr[2][2];
            #pragma unroll
            for (int g = 0; g < 2; ++g) {
                const int qmin = qtile * 128 + w * 32 + g * 16;
                const int q = qmin + lo;
                float p[4][4];
                float pm = -3e38f;
                if (kt * 64 + 63 > qmin) {  // diagonal tile: apply causal mask
                    #pragma unroll
                    for (int n = 0; n < 4; ++n)
                        #pragma unroll
                        for (int r = 0; r < 4; ++r) {
                            int k = kt * 64 + hi * 8 + ((n & 1) << 2) + r + ((n >> 1) << 5);
                            float sv = (k > q) ? -3e38f : sacc[g][n][r];
                            p[n][r] = sv;
                            pm = fmaxf(pm, sv);
                        }
                } else {
                    #pragma unroll
                    for (int n = 0; n < 4; ++n)
                        #pragma unroll
                        for (int r = 0; r < 4; ++r) {
                            p[n][r] = sacc[g][n][r];
                            pm = fmaxf(pm, p[n][r]);
                        }
                }
                pm = fmaxf(pm, __shfl_xor(pm, 16, 64));
                pm = fmaxf(pm, __shfl_xor(pm, 32, 64));
                if (!__all(pm <= m_run[g] + 8.f)) {  // defer-max: rescale rarely
                    float mn = fmaxf(m_run[g], pm);
                    float al = exp2v(m_run[g] - mn);
                    m_run[g] = mn;
                    l_run[g] *= al;
                    float alq[4];
                    #pragma unroll
                    for (int r = 0; r < 4; ++r)
                        alq[r] = __shfl(al, (l & 48) | (hi * 4 + r), 64);
                    #pragma unroll
                    for (int nd = 0; nd < 4; ++nd) {
                        oacc[g][nd][0] *= alq[0]; oacc[g][nd][1] *= alq[1];
                        oacc[g][nd][2] *= alq[2]; oacc[g][nd][3] *= alq[3];
                    }
                }
                float rsum = 0.f;
                #pragma unroll
                for (int n = 0; n < 4; ++n)
                    #pragma unroll
                    for (int r = 0; r < 4; ++r) {
                        float e = exp2v(p[n][r] - m_run[g]);
                        p[n][r] = e;
                        rsum += e;
                    }
                rsum += __shfl_xor(rsum, 16, 64);
                rsum += __shfl_xor(rsum, 32, 64);
                l_run[g] += rsum;
                #pragma unroll
                for (int ks = 0; ks < 2; ++ks) {
                    short8 a;
                    a[0] = f2bs(p[2 * ks][0]);     a[1] = f2bs(p[2 * ks][1]);
                    a[2] = f2bs(p[2 * ks][2]);     a[3] = f2bs(p[2 * ks][3]);
                    a[4] = f2bs(p[2 * ks + 1][0]); a[5] = f2bs(p[2 * ks + 1][1]);
                    a[6] = f2bs(p[2 * ks + 1][2]); a[7] = f2bs(p[2 * ks + 1][3]);
                    afr[g][ks] = a;
                }
            }

            // O += P V
            __builtin_amdgcn_s_setprio(1);
            #pragma unroll
            for (int ks = 0; ks < 2; ++ks) {
                const int slot = ks * 4 + hi;
                #pragma unroll
                for (int nd = 0; nd < 4; ++nd) {
                    const int vrow = nd * 16 + lo;
                    short8 vf = *(const short8*)(Vs + vrow * 64 + ((slot ^ SW(vrow)) << 3));
                    oacc[0][nd] = MFMA(afr[0][ks], vf, oacc[0][nd]);
                    oacc[1][nd] = MFMA(afr[1][ks], vf, oacc[1][nd]);
                }
            }
            __builtin_amdgcn_s_setprio(0);

            __syncthreads();   // drains prefetch vmcnt + releases buf[cur] for overwrite
            cur ^= 1;
        }

        // epilogue for this qtile
        #pragma unroll
        for (int g = 0; g < 2; ++g) {
            float rl[4];
            #pragma unroll
            for (int r = 0; r < 4; ++r)
                rl[r] = 1.0f / __shfl(l_run[g], (l & 48) | (hi * 4 + r), 64);
            #pragma unroll
            for (int nd = 0; nd < 4; ++nd)
                #pragma unroll
                for (int r = 0; r < 4; ++r) {
                    int s = qtile * 128 + w * 32 + g * 16 + hi * 4 + r;
                    Ab[abase + (size_t)s * 2048 + nd * 16 + lo] = f2bs(oacc[g][nd][r] * rl[r]);
                }
        }
    }
}

extern "C" void kernel_launch(void* const* d_in, const int* in_sizes, int n_in,
                              void* d_out, int out_size, void* d_ws, size_t ws_size,
                              hipStream_t stream)
{
    const float* x  = (const float*)d_in[0];
    const float* Wq = (const float*)d_in[1];
    const float* Wk = (const float*)d_in[2];
    const float* Wv = (const float*)d_in[3];
    const float* Wo = (const float*)d_in[4];
    const float* rc = (const float*)d_in[5];
    const float* rs = (const float*)d_in[6];
    float* out = (float*)d_out;
    char* ws = (char*)d_ws;

    size_t off = 0;
    short* x_bf   = (short*)(ws + off); off += (size_t)4096 * 2048 * 2;
    short* Wqkv_t = (short*)(ws + off); off += (size_t)3072 * 2048 * 2;
    short* Wo_t   = (short*)(ws + off); off += (size_t)2048 * 2048 * 2;
    short* Qp     = (short*)(ws + off); off += (size_t)2 * 32 * 2048 * 64 * 2;
    short* Kp     = (short*)(ws + off); off += (size_t)2 * 8 * 2048 * 64 * 2;
    short* Vtb    = (short*)(ws + off); off += (size_t)2 * 8 * 64 * 2048 * 2;
    short* Ab     = (short*)(ws + off); off += (size_t)4096 * 2048 * 2;
    if (off > ws_size) return;

    const int LDS_BYTES = 3 * 24576 * 2;   // 144 KB ring-of-3
    (void)hipFuncSetAttribute((const void*)gemm_k,
                              hipFuncAttributeMaxDynamicSharedMemorySize, LDS_BYTES);

    cast_bf16_k<<<8192, 256, 0, stream>>>(x, x_bf, 2097152);
    transpose_cast_k<<<dim3(64, 64), dim3(32, 8), 0, stream>>>(Wq, Wqkv_t, 2048, 2048);
    transpose_cast_k<<<dim3(16, 64), dim3(32, 8), 0, stream>>>(Wk, Wqkv_t + (size_t)2048 * 2048, 2048, 512);
    transpose_cast_k<<<dim3(16, 64), dim3(32, 8), 0, stream>>>(Wv, Wqkv_t + (size_t)2560 * 2048, 2048, 512);
    transpose_cast_k<<<dim3(64, 64), dim3(32, 8), 0, stream>>>(Wo, Wo_t, 2048, 2048);

    // merged QKV projection: Q rope*SCL pack | K rope pack | V transpose pack
    gemm_k<<<dim3(16, 24), 512, LDS_BYTES, stream>>>(x_bf, Wqkv_t, nullptr, Qp, Kp, Vtb,
                                                     rc, rs, 4096, 3072, 2048, 4);

    attn_k<<<dim3(8, 32, 2), 256, 0, stream>>>(Qp, Kp, Vtb, Ab);

    gemm_k<<<dim3(16, 16), 512, LDS_BYTES, stream>>>(Ab, Wo_t, out, nullptr, nullptr, nullptr,
                                                     nullptr, nullptr, 4096, 2048, 2048, 0);
}